// Round 4
// baseline (1261.251 us; speedup 1.0000x reference)
//
#include <hip/hip_runtime.h>
#include <cstdint>
#include <cstddef>

#define DIM   512
#define HEADS 8
#define HD    64
#define FF    2048
#define WINSZ 128
#define BB    8
#define NN    8192
#define NW    (NN / WINSZ)     // 64
#define MROWS (BB * NN)        // 65536
#define QS    ((size_t)BB * HEADS * NN * HD)  // elems per q/k/v tensor

typedef __attribute__((ext_vector_type(8))) _Float16 half8;
typedef __attribute__((ext_vector_type(4))) float floatx4;

__device__ __forceinline__ floatx4 mfma16(half8 a, half8 b, floatx4 c) {
    return __builtin_amdgcn_mfma_f32_16x16x32_f16(a, b, c, 0, 0, 0);
}

__device__ __forceinline__ void gload_lds16(const void* g, void* l) {
    __builtin_amdgcn_global_load_lds(
        (const __attribute__((address_space(1))) void*)g,
        (__attribute__((address_space(3))) void*)l, 16, 0, 0);
}

__device__ __forceinline__ float qmax16(float v) {
    v = fmaxf(v, __shfl_xor(v, 1));
    v = fmaxf(v, __shfl_xor(v, 2));
    v = fmaxf(v, __shfl_xor(v, 4));
    v = fmaxf(v, __shfl_xor(v, 8));
    return v;
}
__device__ __forceinline__ float qsum16(float v) {
    v += __shfl_xor(v, 1);
    v += __shfl_xor(v, 2);
    v += __shfl_xor(v, 4);
    v += __shfl_xor(v, 8);
    return v;
}

// tanh-form GELU, max abs err ~3e-4 vs exact
__device__ __forceinline__ float gelu_f(float x) {
    const float y = 1.5957691216f * (x + 0.044715f * x * x * x);
    const float t = 1.0f - 2.0f / (__expf(y) + 1.0f);
    return 0.5f * x * (1.0f + t);
}

// raw barrier (NO implicit vmcnt drain, unlike __syncthreads) with scheduler pin
#define SBAR() do { __builtin_amdgcn_sched_barrier(0); \
                    __builtin_amdgcn_s_barrier();      \
                    __builtin_amdgcn_sched_barrier(0); } while (0)

// ---------------------------------------------------------------------------
// ss[b][j] = silu(t_emb[b]) @ time_w[:, j] + time_b[j]   (j < 1024)
__global__ __launch_bounds__(128)
void time_ss_kernel(const float* __restrict__ t_emb, const float* __restrict__ tw,
                    const float* __restrict__ tb, float* __restrict__ ss) {
    __shared__ float st[512];
    const int b = blockIdx.x;
    for (int i = threadIdx.x; i < 512; i += 128) {
        float v = t_emb[b * 512 + i];
        st[i] = v / (1.0f + expf(-v));
    }
    __syncthreads();
    const int j = blockIdx.y * 128 + threadIdx.x;
    float acc = tb[j];
    for (int i = 0; i < 512; ++i) acc += st[i] * tw[i * 1024 + j];
    ss[b * 1024 + j] = acc;
}

// ---------------------------------------------------------------------------
// weight cast+transpose via LDS tile: w f32 [K][N] -> wt f16 [N][K]
__global__ __launch_bounds__(256)
void wcast_kernel(const float* __restrict__ w, _Float16* __restrict__ wt, int K, int N) {
    __shared__ float t[32][33];
    const int kb = blockIdx.x * 32, nb = blockIdx.y * 32;
    const int tx = threadIdx.x & 31, ty = threadIdx.x >> 5;
#pragma unroll
    for (int i = 0; i < 32; i += 8)
        t[ty + i][tx] = w[(size_t)(kb + ty + i) * N + nb + tx];
    __syncthreads();
#pragma unroll
    for (int i = 0; i < 32; i += 8)
        wt[(size_t)(nb + ty + i) * K + kb + tx] = (_Float16)t[tx][ty + i];
}

// ---------------------------------------------------------------------------
// LayerNorm + FiLM, f32 input, one wave per row, f16 out  (LN1)
__global__ __launch_bounds__(256)
void ln_kernel(const float* __restrict__ x, const float* __restrict__ g,
               const float* __restrict__ bv, const float* __restrict__ ss,
               _Float16* __restrict__ out) {
    const int row  = blockIdx.x * 4 + (threadIdx.x >> 6);
    const int lane = threadIdx.x & 63;
    const float* xr = x + (size_t)row * DIM;
    const float4 v0 = *(const float4*)(xr + lane * 4);
    const float4 v1 = *(const float4*)(xr + 256 + lane * 4);
    float s  = v0.x + v0.y + v0.z + v0.w + v1.x + v1.y + v1.z + v1.w;
    float s2 = v0.x * v0.x + v0.y * v0.y + v0.z * v0.z + v0.w * v0.w +
               v1.x * v1.x + v1.y * v1.y + v1.z * v1.z + v1.w * v1.w;
#pragma unroll
    for (int m = 1; m < 64; m <<= 1) {
        s  += __shfl_xor(s, m);
        s2 += __shfl_xor(s2, m);
    }
    const float mean = s * (1.0f / 512.0f);
    const float var  = s2 * (1.0f / 512.0f) - mean * mean;
    const float rstd = rsqrtf(var + 1e-5f);
    const int b = row >> 13;
    const float vv[8] = {v0.x, v0.y, v0.z, v0.w, v1.x, v1.y, v1.z, v1.w};
    union { _Float16 h[4]; unsigned long long u; } pk;
#pragma unroll
    for (int half = 0; half < 2; ++half) {
        const int c0 = half * 256 + lane * 4;
#pragma unroll
        for (int i = 0; i < 4; ++i) {
            const int c = c0 + i;
            float y = (vv[half * 4 + i] - mean) * rstd * g[c] + bv[c];
            y = y * (1.0f + ss[b * 1024 + c]) + ss[b * 1024 + 512 + c];
            pk.h[i] = (_Float16)y;
        }
        *(unsigned long long*)(out + (size_t)row * DIM + c0) = pk.u;
    }
}

// LayerNorm, f16 input, one wave per row, f16 out  (LN2)
__global__ __launch_bounds__(256)
void ln_h_kernel(const _Float16* __restrict__ x, const float* __restrict__ g,
                 const float* __restrict__ bv, _Float16* __restrict__ out) {
    const int row  = blockIdx.x * 4 + (threadIdx.x >> 6);
    const int lane = threadIdx.x & 63;
    half8 v = *(const half8*)(x + (size_t)row * DIM + lane * 8);
    float f[8];
    float s = 0.f, s2 = 0.f;
#pragma unroll
    for (int i = 0; i < 8; ++i) {
        f[i] = (float)v[i];
        s += f[i];
        s2 += f[i] * f[i];
    }
#pragma unroll
    for (int m = 1; m < 64; m <<= 1) {
        s  += __shfl_xor(s, m);
        s2 += __shfl_xor(s2, m);
    }
    const float mean = s * (1.0f / 512.0f);
    const float var  = s2 * (1.0f / 512.0f) - mean * mean;
    const float rstd = rsqrtf(var + 1e-5f);
    half8 o;
#pragma unroll
    for (int i = 0; i < 8; ++i) {
        const int c = lane * 8 + i;
        o[i] = (_Float16)((f[i] - mean) * rstd * g[c] + bv[c]);
    }
    *(half8*)(out + (size_t)row * DIM + lane * 8) = o;
}

// ---------------------------------------------------------------------------
// GEMM, 256x128 tile, BK=32, 8 waves (4M x 2N, 64x64 each), minimal 2-phase
// pipeline: 3-buffer LDS (72 KiB -> 2 blocks/CU, 4 waves/SIMD), one barrier
// per K-tile, counted vmcnt(3) (2-tile prefetch depth), setprio around MFMA,
// XCD-aware block swizzle, corrected LDS XOR swizzle (qd ^ ((row>>1)&3)).
//
//   tile t:  stage(t+2) -> buf[(t+2)%3]     (3 gload_lds per wave)
//            ds_read frags  <- buf[t%3]     (8 ds_read_b128)
//            16 MFMA
//            s_waitcnt vmcnt(3)             (forces tile t+1 loads complete)
//            s_barrier                      (publishes them to all waves)
//
// EPI 0: scatter to q/k/v f16    EPI 1: + residf(f32) -> f16
// EPI 2: gelu -> f16             EPI 3: + residh(f16) -> f32 (final out)
template <int EPI>
__global__ __launch_bounds__(512, 4)
void gemm_bt(const _Float16* __restrict__ A, const _Float16* __restrict__ BT,
             const float* __restrict__ bias, int K, int N,
             const float* __restrict__ residf, const _Float16* __restrict__ residh,
             float* __restrict__ outf, _Float16* __restrict__ outh) {
    __shared__ __align__(16) _Float16 lds[36864];   // 72 KiB: 3 x (A 16K + B 8K)
    const int tid  = threadIdx.x;
    const int wv   = tid >> 6;
    const int lane = tid & 63;
    const int ln   = lane & 15;
    const int qd   = lane >> 4;
    const int wr   = wv >> 1;        // M quarter (0..3), 64 rows
    const int wc   = wv & 1;         // N half    (0..1), 64 cols
    const int NT   = K >> 5;         // K-tiles (16 or 64)

    // XCD swizzle: 8 consecutive M-tiles share l%8 (one per XCD), walk cols.
    const int nbx = gridDim.x;
    const int l   = blockIdx.y * nbx + blockIdx.x;
    const int grp = l / (nbx * 8);
    const int rem = l - grp * (nbx * 8);
    const int m0  = (grp * 8 + (rem & 7)) * 256;
    const int n0  = (rem >> 3) * 128;

    // staging: A tile 256x32 f16 = 1024 16B-chunks (2/thread), B tile 128x32
    // = 512 chunks (1/thread). chunk c -> row c>>2, slot c&3; source slot =
    // (c&3) ^ ((row>>1)&3)  (involution, matches read-side swizzle).
    const int ca0 = wv * 128 + lane;
    const int ca1 = ca0 + 64;
    const int cb  = wv * 64 + lane;
    const int ra0 = ca0 >> 2, ra1 = ca1 >> 2, rb = cb >> 2;
    const _Float16* aP0 = A + (size_t)(m0 + ra0) * K + (((ca0 & 3) ^ ((ra0 >> 1) & 3)) << 3);
    const _Float16* aP1 = A + (size_t)(m0 + ra1) * K + (((ca1 & 3) ^ ((ra1 >> 1) & 3)) << 3);
    const _Float16* bP  = BT + (size_t)(n0 + rb) * K + (((cb & 3) ^ ((rb >> 1) & 3)) << 3);
    const int dA0 = wv * 1024;           // wave-uniform LDS elem bases
    const int dA1 = wv * 1024 + 512;
    const int dB  = 8192 + wv * 512;

    auto stage = [&](int base, int ke) {   // 3 loads per wave
        gload_lds16(aP0 + ke, &lds[base + dA0]);
        gload_lds16(aP1 + ke, &lds[base + dA1]);
        gload_lds16(bP  + ke, &lds[base + dB]);
    };

    // fragment read offsets (loop-invariant)
    int rA[4], rB[4];
#pragma unroll
    for (int f = 0; f < 4; ++f) {
        const int row = wr * 64 + f * 16 + ln;
        rA[f] = row * 32 + ((qd ^ ((row >> 1) & 3)) << 3);
    }
#pragma unroll
    for (int n = 0; n < 4; ++n) {
        const int row = wc * 64 + n * 16 + ln;
        rB[n] = 8192 + row * 32 + ((qd ^ ((row >> 1) & 3)) << 3);
    }

    floatx4 acc[4][4];
#pragma unroll
    for (int f = 0; f < 4; ++f)
#pragma unroll
        for (int n = 0; n < 4; ++n) acc[f][n] = (floatx4){0.f, 0.f, 0.f, 0.f};

    // prologue: tiles 0 and 1
    stage(0, 0);
    stage(12288, 32);
    asm volatile("s_waitcnt vmcnt(3)" ::: "memory");   // tile 0 complete
    SBAR();

    int boR = 0, boW = 24576, keW = 64;
    for (int t = 0; t < NT; ++t) {
        const bool more = (t + 2 < NT);
        if (more) stage(boW, keW);
        half8 af[4], bf[4];
#pragma unroll
        for (int f = 0; f < 4; ++f) af[f] = *(const half8*)&lds[boR + rA[f]];
#pragma unroll
        for (int n = 0; n < 4; ++n) bf[n] = *(const half8*)&lds[boR + rB[n]];
        __builtin_amdgcn_s_setprio(1);
#pragma unroll
        for (int f = 0; f < 4; ++f)
#pragma unroll
            for (int n = 0; n < 4; ++n) acc[f][n] = mfma16(af[f], bf[n], acc[f][n]);
        __builtin_amdgcn_s_setprio(0);
        if (more) asm volatile("s_waitcnt vmcnt(3)" ::: "memory");  // t+1 ready
        else      asm volatile("s_waitcnt vmcnt(0)" ::: "memory");
        SBAR();
        boR += 12288; if (boR == 36864) boR = 0;
        boW += 12288; if (boW == 36864) boW = 0;
        keW += 32;
    }

    // epilogue
#pragma unroll
    for (int f = 0; f < 4; ++f) {
#pragma unroll
        for (int n = 0; n < 4; ++n) {
            const int col  = n0 + wc * 64 + n * 16 + ln;
            const float bbv = bias[col];
#pragma unroll
            for (int r = 0; r < 4; ++r) {
                const int row = m0 + wr * 64 + f * 16 + qd * 4 + r;
                const float v = acc[f][n][r] + bbv;
                if (EPI == 0) {
                    const int which = col >> 9, cc = col & 511;
                    const int b = row >> 13, t = row & 8191;
                    const int h = cc >> 6, d = cc & 63;
                    outh[(size_t)which * QS +
                         ((size_t)(b * HEADS + h) * NN + t) * HD + d] = (_Float16)v;
                } else if (EPI == 1) {
                    const size_t idx = (size_t)row * N + col;
                    outh[idx] = (_Float16)(residf[idx] + v);
                } else if (EPI == 3) {
                    const size_t idx = (size_t)row * N + col;
                    outf[idx] = (float)residh[idx] + v;
                } else {  // EPI == 2 : fast GELU
                    outh[(size_t)row * N + col] = (_Float16)gelu_f(v);
                }
            }
        }
    }
}

// ---------------------------------------------------------------------------
// Windowed attention, one block per (window w, b*H+h). 4 waves x 32 q-rows.
// Round-4: no occupancy pin (round-3's (256,4) forced a 64-VGPR split and
// spilled sacc -> 1.2 GB scratch traffic). V^T stored with XOR slot swizzle
// (slot = (s>>3) ^ (d&7)) -> write scatter is 2 lanes/bank (was 16-way);
// reads stay contiguous 16B with identical bank cost.
__global__ __launch_bounds__(256)
void attn_kernel(const _Float16* __restrict__ qkv, _Float16* __restrict__ attn) {
    const int w  = blockIdx.x;
    const int bh = blockIdx.y;
    const int tid  = threadIdx.x;
    const int wv   = tid >> 6;
    const int lane = tid & 63;
    const int ln   = lane & 15;
    const int qd   = lane >> 4;

    __shared__ _Float16 vt[64 * 128];      // V^T [d][slot^], XOR-swizzled (16 KiB)
    __shared__ _Float16 pl[4 * 32 * 72];   // per-wave P k-half (18 KiB)

    const _Float16* qbuf = qkv;
    const _Float16* kbuf = qkv + QS;
    const _Float16* vbuf = qkv + 2 * QS;
    const size_t bhbase = (size_t)bh * NN * HD;

    half8 qf[2][2];
    const _Float16* qsrc = qbuf + bhbase + (size_t)(w * WINSZ + wv * 32) * HD;
#pragma unroll
    for (int mt = 0; mt < 2; ++mt)
#pragma unroll
        for (int ks = 0; ks < 2; ++ks)
            qf[mt][ks] = *(const half8*)(qsrc + (mt * 16 + ln) * HD + ks * 32 + qd * 8);

    float mrun[2][4], lrun[2][4];
    floatx4 oacc[2][4];
#pragma unroll
    for (int mt = 0; mt < 2; ++mt)
#pragma unroll
        for (int r = 0; r < 4; ++r) { mrun[mt][r] = -3.0e38f; lrun[mt][r] = 0.f; }
#pragma unroll
    for (int mt = 0; mt < 2; ++mt)
#pragma unroll
        for (int dt = 0; dt < 4; ++dt) oacc[mt][dt] = (floatx4){0.f, 0.f, 0.f, 0.f};

    for (int c = 0; c < 3; ++c) {
        const int kvw = w + c - 1;
        if (kvw < 0 || kvw >= NW) continue;   // block-uniform: safe with barriers
        __syncthreads();
        const _Float16* vsrc = vbuf + bhbase + (size_t)kvw * WINSZ * HD;
#pragma unroll
        for (int j = 0; j < 4; ++j) {
            const int cc = tid + j * 256;
            const int s = cc >> 3, d0 = (cc & 7) * 8;
            half8 vvv = *(const half8*)(vsrc + cc * 8);
#pragma unroll
            for (int e = 0; e < 8; ++e)   // d = d0+e, d&7 == e
                vt[(d0 + e) * 128 + (((s >> 3) ^ e) << 3) + (s & 7)] = vvv[e];
        }
        __syncthreads();

        const _Float16* ksrc = kbuf + bhbase + (size_t)kvw * WINSZ * HD;
        floatx4 sacc[2][8];
#pragma unroll
        for (int nt = 0; nt < 8; ++nt) {
            half8 b0 = *(const half8*)(ksrc + (nt * 16 + ln) * HD + qd * 8);
            half8 b1 = *(const half8*)(ksrc + (nt * 16 + ln) * HD + 32 + qd * 8);
#pragma unroll
            for (int mt = 0; mt < 2; ++mt) {
                floatx4 t = mfma16(qf[mt][0], b0, (floatx4){0.f, 0.f, 0.f, 0.f});
                sacc[mt][nt] = mfma16(qf[mt][1], b1, t);
            }
        }

        // ---- pass A: running-max update, rescale oacc & lrun ----
#pragma unroll
        for (int mt = 0; mt < 2; ++mt) {
#pragma unroll
            for (int r = 0; r < 4; ++r) {
                float mx = -3.0e38f;
#pragma unroll
                for (int nt = 0; nt < 8; ++nt)
                    mx = fmaxf(mx, sacc[mt][nt][r] * 0.125f);
                mx = qmax16(mx);
                const float mnew  = fmaxf(mrun[mt][r], mx);
                const float alpha = __expf(mrun[mt][r] - mnew);
                mrun[mt][r] = mnew;
                lrun[mt][r] *= alpha;
#pragma unroll
                for (int dt = 0; dt < 4; ++dt) oacc[mt][dt][r] *= alpha;
            }
        }

        // ---- pass B: two k-halves of 64; exp + P store + PV interleaved ----
        _Float16* plw = pl + wv * 32 * 72;
#pragma unroll
        for (int kh = 0; kh < 2; ++kh) {
#pragma unroll
            for (int mt = 0; mt < 2; ++mt) {
#pragma unroll
                for (int r = 0; r < 4; ++r) {
                    float rsl = 0.f;
#pragma unroll
                    for (int n2 = 0; n2 < 4; ++n2) {
                        const int nt = kh * 4 + n2;
                        const float pv = __expf(sacc[mt][nt][r] * 0.125f - mrun[mt][r]);
                        rsl += pv;
                        plw[(mt * 16 + qd * 4 + r) * 72 + n2 * 16 + ln] = (_Float16)pv;
                    }
                    lrun[mt][r] += qsum16(rsl);
                }
            }
#pragma unroll
            for (int ktl = 0; ktl < 2; ++ktl) {
                const int kt = kh * 2 + ktl;
                half8 pf0 = *(const half8*)(plw + ln * 72 + ktl * 32 + qd * 8);
                half8 pf1 = *(const half8*)(plw + (16 + ln) * 72 + ktl * 32 + qd * 8);
                __builtin_amdgcn_s_setprio(1);
#pragma unroll
                for (int dt = 0; dt < 4; ++dt) {
                    const int d = dt * 16 + ln;   // d&7 == ln&7
                    half8 vf = *(const half8*)&vt[d * 128 +
                                (((kt * 4 + qd) ^ (ln & 7)) << 3)];
                    oacc[0][dt] = mfma16(pf0, vf, oacc[0][dt]);
                    oacc[1][dt] = mfma16(pf1, vf, oacc[1][dt]);
                }
                __builtin_amdgcn_s_setprio(0);
            }
        }
    }

    const int b = bh >> 3, h = bh & 7;
#pragma unroll
    for (int mt = 0; mt < 2; ++mt) {
#pragma unroll
        for (int dt = 0; dt < 4; ++dt) {
#pragma unroll
            for (int r = 0; r < 4; ++r) {
                const int trow = w * WINSZ + wv * 32 + mt * 16 + qd * 4 + r;
                const int col  = h * HD + dt * 16 + ln;
                attn[((size_t)b * NN + trow) * DIM + col] =
                    (_Float16)(oacc[mt][dt][r] / lrun[mt][r]);
            }
        }
    }
}

// ---------------------------------------------------------------------------
extern "C" void kernel_launch(void* const* d_in, const int* in_sizes, int n_in,
                              void* d_out, int out_size, void* d_ws, size_t ws_size,
                              hipStream_t stream) {
    const float* x      = (const float*)d_in[0];
    const float* t_emb  = (const float*)d_in[1];
    const float* ln1_g  = (const float*)d_in[2];
    const float* ln1_b  = (const float*)d_in[3];
    const float* qkv_w  = (const float*)d_in[4];
    const float* qkv_b  = (const float*)d_in[5];
    const float* proj_w = (const float*)d_in[6];
    const float* proj_b = (const float*)d_in[7];
    const float* ln2_g  = (const float*)d_in[8];
    const float* ln2_b  = (const float*)d_in[9];
    const float* mlp_w1 = (const float*)d_in[10];
    const float* mlp_b1 = (const float*)d_in[11];
    const float* mlp_w2 = (const float*)d_in[12];
    const float* mlp_b2 = (const float*)d_in[13];
    const float* time_w = (const float*)d_in[14];
    const float* time_b = (const float*)d_in[15];
    float* out = (float*)d_out;

    char* p = (char*)d_ws;
    auto alloc = [&](size_t bytes) {
        char* r = p;
        p += (bytes + 255) & ~(size_t)255;
        return r;
    };
    float*    ss   = (float*)alloc(8 * 1024 * 4);
    _Float16* wq   = (_Float16*)alloc((size_t)1536 * 512 * 2);
    _Float16* wp   = (_Float16*)alloc((size_t)512 * 512 * 2);
    _Float16* w1t  = (_Float16*)alloc((size_t)2048 * 512 * 2);
    _Float16* w2t  = (_Float16*)alloc((size_t)512 * 2048 * 2);
    _Float16* h2   = (_Float16*)alloc((size_t)MROWS * 512 * 2);
    _Float16* x1h  = (_Float16*)alloc((size_t)MROWS * 512 * 2);
    _Float16* regA = (_Float16*)alloc((size_t)MROWS * 512 * 2);      // xn / attn
    _Float16* regB = (_Float16*)alloc((size_t)3 * MROWS * 512 * 2);  // q,k,v
    _Float16* xn     = regA;
    _Float16* attn   = regA;
    _Float16* qkvb   = regB;
    _Float16* hidden = regA;  // 268 MB = regA(67) + regB(201), both dead by then
    (void)ws_size; (void)in_sizes; (void)n_in; (void)out_size;

    // 1. weight casts/transposes (f32 [K][N] -> f16 [N][K]), LDS-tiled
    wcast_kernel<<<dim3(512 / 32, 1536 / 32), 256, 0, stream>>>(qkv_w, wq, 512, 1536);
    wcast_kernel<<<dim3(512 / 32, 512 / 32), 256, 0, stream>>>(proj_w, wp, 512, 512);
    wcast_kernel<<<dim3(512 / 32, 2048 / 32), 256, 0, stream>>>(mlp_w1, w1t, 512, 2048);
    wcast_kernel<<<dim3(2048 / 32, 512 / 32), 256, 0, stream>>>(mlp_w2, w2t, 2048, 512);
    // 2. time modulation
    time_ss_kernel<<<dim3(8, 8), 128, 0, stream>>>(t_emb, time_w, time_b, ss);
    // 3. LN1 + FiLM -> xn (f16)
    ln_kernel<<<dim3(MROWS / 4), 256, 0, stream>>>(x, ln1_g, ln1_b, ss, xn);
    // 4. QKV GEMM with q/k/v scatter  (256x128 tiles, 512 threads)
    gemm_bt<0><<<dim3(1536 / 128, MROWS / 256), 512, 0, stream>>>(
        xn, wq, qkv_b, 512, 1536, nullptr, nullptr, nullptr, qkvb);
    // 5. windowed attention -> attn (f16, [B][N][DIM])
    attn_kernel<<<dim3(NW, BB * HEADS), 256, 0, stream>>>(qkvb, attn);
    // 6. proj GEMM + residual(x f32) -> x1h (f16)
    gemm_bt<1><<<dim3(512 / 128, MROWS / 256), 512, 0, stream>>>(
        attn, wp, proj_b, 512, 512, x, nullptr, nullptr, x1h);
    // 7. LN2 (f16 in) -> h2 (f16)
    ln_h_kernel<<<dim3(MROWS / 4), 256, 0, stream>>>(x1h, ln2_g, ln2_b, h2);
    // 8. MLP1 + fast GELU -> hidden (f16)
    gemm_bt<2><<<dim3(2048 / 128, MROWS / 256), 512, 0, stream>>>(
        h2, w1t, mlp_b1, 512, 2048, nullptr, nullptr, nullptr, hidden);
    // 9. MLP2 + residual(x1h f16) -> out (f32)
    gemm_bt<3><<<dim3(512 / 128, MROWS / 256), 512, 0, stream>>>(
        hidden, w2t, mlp_b2, 2048, 512, nullptr, x1h, out, nullptr);
}

// Round 6
// 1108.025 us; speedup vs baseline: 1.1383x; 1.1383x over previous
//
#include <hip/hip_runtime.h>
#include <cstdint>
#include <cstddef>

#define DIM   512
#define HEADS 8
#define HD    64
#define FF    2048
#define WINSZ 128
#define BB    8
#define NN    8192
#define NW    (NN / WINSZ)     // 64
#define MROWS (BB * NN)        // 65536
#define QS    ((size_t)BB * HEADS * NN * HD)  // elems per q/k/v tensor

typedef __attribute__((ext_vector_type(8))) _Float16 half8;
typedef __attribute__((ext_vector_type(4))) float floatx4;

__device__ __forceinline__ floatx4 mfma16(half8 a, half8 b, floatx4 c) {
    return __builtin_amdgcn_mfma_f32_16x16x32_f16(a, b, c, 0, 0, 0);
}

__device__ __forceinline__ void gload_lds16(const void* g, void* l) {
    __builtin_amdgcn_global_load_lds(
        (const __attribute__((address_space(1))) void*)g,
        (__attribute__((address_space(3))) void*)l, 16, 0, 0);
}

__device__ __forceinline__ float qmax16(float v) {
    v = fmaxf(v, __shfl_xor(v, 1));
    v = fmaxf(v, __shfl_xor(v, 2));
    v = fmaxf(v, __shfl_xor(v, 4));
    v = fmaxf(v, __shfl_xor(v, 8));
    return v;
}
__device__ __forceinline__ float qsum16(float v) {
    v += __shfl_xor(v, 1);
    v += __shfl_xor(v, 2);
    v += __shfl_xor(v, 4);
    v += __shfl_xor(v, 8);
    return v;
}

// tanh-form GELU, max abs err ~3e-4 vs exact
__device__ __forceinline__ float gelu_f(float x) {
    const float y = 1.5957691216f * (x + 0.044715f * x * x * x);
    const float t = 1.0f - 2.0f / (__expf(y) + 1.0f);
    return 0.5f * x * (1.0f + t);
}

// raw barrier (NO implicit vmcnt drain, unlike __syncthreads) with scheduler pin
#define SBAR() do { __builtin_amdgcn_sched_barrier(0); \
                    __builtin_amdgcn_s_barrier();      \
                    __builtin_amdgcn_sched_barrier(0); } while (0)

// ---------------------------------------------------------------------------
// ss[b][j] = silu(t_emb[b]) @ time_w[:, j] + time_b[j]   (j < 1024)
__global__ __launch_bounds__(128)
void time_ss_kernel(const float* __restrict__ t_emb, const float* __restrict__ tw,
                    const float* __restrict__ tb, float* __restrict__ ss) {
    __shared__ float st[512];
    const int b = blockIdx.x;
    for (int i = threadIdx.x; i < 512; i += 128) {
        float v = t_emb[b * 512 + i];
        st[i] = v / (1.0f + expf(-v));
    }
    __syncthreads();
    const int j = blockIdx.y * 128 + threadIdx.x;
    float acc = tb[j];
    for (int i = 0; i < 512; ++i) acc += st[i] * tw[i * 1024 + j];
    ss[b * 1024 + j] = acc;
}

// ---------------------------------------------------------------------------
// weight cast+transpose via LDS tile: w f32 [K][N] -> wt f16 [N][K]
__global__ __launch_bounds__(256)
void wcast_kernel(const float* __restrict__ w, _Float16* __restrict__ wt, int K, int N) {
    __shared__ float t[32][33];
    const int kb = blockIdx.x * 32, nb = blockIdx.y * 32;
    const int tx = threadIdx.x & 31, ty = threadIdx.x >> 5;
#pragma unroll
    for (int i = 0; i < 32; i += 8)
        t[ty + i][tx] = w[(size_t)(kb + ty + i) * N + nb + tx];
    __syncthreads();
#pragma unroll
    for (int i = 0; i < 32; i += 8)
        wt[(size_t)(nb + ty + i) * K + kb + tx] = (_Float16)t[tx][ty + i];
}

// ---------------------------------------------------------------------------
// LayerNorm + FiLM, f32 input, one wave per row, f16 out  (LN1)
__global__ __launch_bounds__(256)
void ln_kernel(const float* __restrict__ x, const float* __restrict__ g,
               const float* __restrict__ bv, const float* __restrict__ ss,
               _Float16* __restrict__ out) {
    const int row  = blockIdx.x * 4 + (threadIdx.x >> 6);
    const int lane = threadIdx.x & 63;
    const float* xr = x + (size_t)row * DIM;
    const float4 v0 = *(const float4*)(xr + lane * 4);
    const float4 v1 = *(const float4*)(xr + 256 + lane * 4);
    float s  = v0.x + v0.y + v0.z + v0.w + v1.x + v1.y + v1.z + v1.w;
    float s2 = v0.x * v0.x + v0.y * v0.y + v0.z * v0.z + v0.w * v0.w +
               v1.x * v1.x + v1.y * v1.y + v1.z * v1.z + v1.w * v1.w;
#pragma unroll
    for (int m = 1; m < 64; m <<= 1) {
        s  += __shfl_xor(s, m);
        s2 += __shfl_xor(s2, m);
    }
    const float mean = s * (1.0f / 512.0f);
    const float var  = s2 * (1.0f / 512.0f) - mean * mean;
    const float rstd = rsqrtf(var + 1e-5f);
    const int b = row >> 13;
    const float vv[8] = {v0.x, v0.y, v0.z, v0.w, v1.x, v1.y, v1.z, v1.w};
    union { _Float16 h[4]; unsigned long long u; } pk;
#pragma unroll
    for (int half = 0; half < 2; ++half) {
        const int c0 = half * 256 + lane * 4;
#pragma unroll
        for (int i = 0; i < 4; ++i) {
            const int c = c0 + i;
            float y = (vv[half * 4 + i] - mean) * rstd * g[c] + bv[c];
            y = y * (1.0f + ss[b * 1024 + c]) + ss[b * 1024 + 512 + c];
            pk.h[i] = (_Float16)y;
        }
        *(unsigned long long*)(out + (size_t)row * DIM + c0) = pk.u;
    }
}

// LayerNorm, f16 input, one wave per row, f16 out  (LN2)
__global__ __launch_bounds__(256)
void ln_h_kernel(const _Float16* __restrict__ x, const float* __restrict__ g,
                 const float* __restrict__ bv, _Float16* __restrict__ out) {
    const int row  = blockIdx.x * 4 + (threadIdx.x >> 6);
    const int lane = threadIdx.x & 63;
    half8 v = *(const half8*)(x + (size_t)row * DIM + lane * 8);
    float f[8];
    float s = 0.f, s2 = 0.f;
#pragma unroll
    for (int i = 0; i < 8; ++i) {
        f[i] = (float)v[i];
        s += f[i];
        s2 += f[i] * f[i];
    }
#pragma unroll
    for (int m = 1; m < 64; m <<= 1) {
        s  += __shfl_xor(s, m);
        s2 += __shfl_xor(s2, m);
    }
    const float mean = s * (1.0f / 512.0f);
    const float var  = s2 * (1.0f / 512.0f) - mean * mean;
    const float rstd = rsqrtf(var + 1e-5f);
    half8 o;
#pragma unroll
    for (int i = 0; i < 8; ++i) {
        const int c = lane * 8 + i;
        o[i] = (_Float16)((f[i] - mean) * rstd * g[c] + bv[c]);
    }
    *(half8*)(out + (size_t)row * DIM + lane * 8) = o;
}

// ---------------------------------------------------------------------------
// GEMM, 256x128 tile, BK=32, 8 waves (4M x 2N, 64x64 each), minimal 2-phase
// pipeline: 3-buffer LDS (72 KiB -> 2 blocks/CU, 4 waves/SIMD), one barrier
// per K-tile, counted vmcnt(3) (2-tile prefetch depth), setprio around MFMA,
// XCD-aware block swizzle, corrected LDS XOR swizzle (qd ^ ((row>>1)&3)).
//
//   tile t:  stage(t+2) -> buf[(t+2)%3]     (3 gload_lds per wave)
//            ds_read frags  <- buf[t%3]     (8 ds_read_b128)
//            16 MFMA
//            s_waitcnt vmcnt(3)             (forces tile t+1 loads complete)
//            s_barrier                      (publishes them to all waves)
//
// EPI 0: scatter to q/k/v f16    EPI 1: + residf(f32) -> f16
// EPI 2: gelu -> f16             EPI 3: + residh(f16) -> f32 (final out)
template <int EPI>
__global__ __launch_bounds__(512, 4)
void gemm_bt(const _Float16* __restrict__ A, const _Float16* __restrict__ BT,
             const float* __restrict__ bias, int K, int N,
             const float* __restrict__ residf, const _Float16* __restrict__ residh,
             float* __restrict__ outf, _Float16* __restrict__ outh) {
    __shared__ __align__(16) _Float16 lds[36864];   // 72 KiB: 3 x (A 16K + B 8K)
    const int tid  = threadIdx.x;
    const int wv   = tid >> 6;
    const int lane = tid & 63;
    const int ln   = lane & 15;
    const int qd   = lane >> 4;
    const int wr   = wv >> 1;        // M quarter (0..3), 64 rows
    const int wc   = wv & 1;         // N half    (0..1), 64 cols
    const int NT   = K >> 5;         // K-tiles (16 or 64)

    // XCD swizzle: 8 consecutive M-tiles share l%8 (one per XCD), walk cols.
    const int nbx = gridDim.x;
    const int l   = blockIdx.y * nbx + blockIdx.x;
    const int grp = l / (nbx * 8);
    const int rem = l - grp * (nbx * 8);
    const int m0  = (grp * 8 + (rem & 7)) * 256;
    const int n0  = (rem >> 3) * 128;

    // staging: A tile 256x32 f16 = 1024 16B-chunks (2/thread), B tile 128x32
    // = 512 chunks (1/thread). chunk c -> row c>>2, slot c&3; source slot =
    // (c&3) ^ ((row>>1)&3)  (involution, matches read-side swizzle).
    const int ca0 = wv * 128 + lane;
    const int ca1 = ca0 + 64;
    const int cb  = wv * 64 + lane;
    const int ra0 = ca0 >> 2, ra1 = ca1 >> 2, rb = cb >> 2;
    const _Float16* aP0 = A + (size_t)(m0 + ra0) * K + (((ca0 & 3) ^ ((ra0 >> 1) & 3)) << 3);
    const _Float16* aP1 = A + (size_t)(m0 + ra1) * K + (((ca1 & 3) ^ ((ra1 >> 1) & 3)) << 3);
    const _Float16* bP  = BT + (size_t)(n0 + rb) * K + (((cb & 3) ^ ((rb >> 1) & 3)) << 3);
    const int dA0 = wv * 1024;           // wave-uniform LDS elem bases
    const int dA1 = wv * 1024 + 512;
    const int dB  = 8192 + wv * 512;

    auto stage = [&](int base, int ke) {   // 3 loads per wave
        gload_lds16(aP0 + ke, &lds[base + dA0]);
        gload_lds16(aP1 + ke, &lds[base + dA1]);
        gload_lds16(bP  + ke, &lds[base + dB]);
    };

    // fragment read offsets (loop-invariant)
    int rA[4], rB[4];
#pragma unroll
    for (int f = 0; f < 4; ++f) {
        const int row = wr * 64 + f * 16 + ln;
        rA[f] = row * 32 + ((qd ^ ((row >> 1) & 3)) << 3);
    }
#pragma unroll
    for (int n = 0; n < 4; ++n) {
        const int row = wc * 64 + n * 16 + ln;
        rB[n] = 8192 + row * 32 + ((qd ^ ((row >> 1) & 3)) << 3);
    }

    floatx4 acc[4][4];
#pragma unroll
    for (int f = 0; f < 4; ++f)
#pragma unroll
        for (int n = 0; n < 4; ++n) acc[f][n] = (floatx4){0.f, 0.f, 0.f, 0.f};

    // prologue: tiles 0 and 1
    stage(0, 0);
    stage(12288, 32);
    asm volatile("s_waitcnt vmcnt(3)" ::: "memory");   // tile 0 complete
    SBAR();

    int boR = 0, boW = 24576, keW = 64;
    for (int t = 0; t < NT; ++t) {
        const bool more = (t + 2 < NT);
        if (more) stage(boW, keW);
        half8 af[4], bf[4];
#pragma unroll
        for (int f = 0; f < 4; ++f) af[f] = *(const half8*)&lds[boR + rA[f]];
#pragma unroll
        for (int n = 0; n < 4; ++n) bf[n] = *(const half8*)&lds[boR + rB[n]];
        __builtin_amdgcn_s_setprio(1);
#pragma unroll
        for (int f = 0; f < 4; ++f)
#pragma unroll
            for (int n = 0; n < 4; ++n) acc[f][n] = mfma16(af[f], bf[n], acc[f][n]);
        __builtin_amdgcn_s_setprio(0);
        if (more) asm volatile("s_waitcnt vmcnt(3)" ::: "memory");  // t+1 ready
        else      asm volatile("s_waitcnt vmcnt(0)" ::: "memory");
        SBAR();
        boR += 12288; if (boR == 36864) boR = 0;
        boW += 12288; if (boW == 36864) boW = 0;
        keW += 32;
    }

    // epilogue
#pragma unroll
    for (int f = 0; f < 4; ++f) {
#pragma unroll
        for (int n = 0; n < 4; ++n) {
            const int col  = n0 + wc * 64 + n * 16 + ln;
            const float bbv = bias[col];
#pragma unroll
            for (int r = 0; r < 4; ++r) {
                const int row = m0 + wr * 64 + f * 16 + qd * 4 + r;
                const float v = acc[f][n][r] + bbv;
                if (EPI == 0) {
                    const int which = col >> 9, cc = col & 511;
                    const int b = row >> 13, t = row & 8191;
                    const int h = cc >> 6, d = cc & 63;
                    outh[(size_t)which * QS +
                         ((size_t)(b * HEADS + h) * NN + t) * HD + d] = (_Float16)v;
                } else if (EPI == 1) {
                    const size_t idx = (size_t)row * N + col;
                    outh[idx] = (_Float16)(residf[idx] + v);
                } else if (EPI == 3) {
                    const size_t idx = (size_t)row * N + col;
                    outf[idx] = (float)residh[idx] + v;
                } else {  // EPI == 2 : fast GELU
                    outh[(size_t)row * N + col] = (_Float16)gelu_f(v);
                }
            }
        }
    }
}

// ---------------------------------------------------------------------------
// Windowed attention, one block per (window w, b*H+h). 4 waves x 32 q-rows.
// Round-6 == round-5 resubmit (round-5 bench was an infra failure, not a
// kernel failure): exact round-2 structure (monolithic online softmax,
// pl[136], no occupancy pin) + lane-varying V^T XOR swizzle. Write key
// lane&7 equals the read key (d>>3)&7 (d0 = (lane&7)*8), so both sides
// apply the same involution. Write: 2 lanes/bank (was 16-way).
__global__ __launch_bounds__(256)
void attn_kernel(const _Float16* __restrict__ qkv, _Float16* __restrict__ attn) {
    const int w  = blockIdx.x;
    const int bh = blockIdx.y;
    const int tid  = threadIdx.x;
    const int wv   = tid >> 6;
    const int lane = tid & 63;
    const int ln   = lane & 15;
    const int qd   = lane >> 4;

    __shared__ _Float16 vt[64 * 136];        // V^T [d][s^], XOR-swizzled slots
    __shared__ _Float16 pl[4 * 32 * 136];    // per-wave P scratch

    const _Float16* qbuf = qkv;
    const _Float16* kbuf = qkv + QS;
    const _Float16* vbuf = qkv + 2 * QS;
    const size_t bhbase = (size_t)bh * NN * HD;

    half8 qf[2][2];
    const _Float16* qsrc = qbuf + bhbase + (size_t)(w * WINSZ + wv * 32) * HD;
#pragma unroll
    for (int mt = 0; mt < 2; ++mt)
#pragma unroll
        for (int ks = 0; ks < 2; ++ks)
            qf[mt][ks] = *(const half8*)(qsrc + (mt * 16 + ln) * HD + ks * 32 + qd * 8);

    float mrun[2][4], lrun[2][4];
    floatx4 oacc[2][4];
#pragma unroll
    for (int mt = 0; mt < 2; ++mt)
#pragma unroll
        for (int r = 0; r < 4; ++r) { mrun[mt][r] = -3.0e38f; lrun[mt][r] = 0.f; }
#pragma unroll
    for (int mt = 0; mt < 2; ++mt)
#pragma unroll
        for (int dt = 0; dt < 4; ++dt) oacc[mt][dt] = (floatx4){0.f, 0.f, 0.f, 0.f};

    const int l7 = lane & 7;     // V^T write swizzle key == (d>>3)&7
    const int h3 = ln >> 3;      // V^T read  swizzle uses (d>>3)&7 = dt*2+h3

    for (int c = 0; c < 3; ++c) {
        const int kvw = w + c - 1;
        if (kvw < 0 || kvw >= NW) continue;   // block-uniform: safe with barriers
        __syncthreads();
        const _Float16* vsrc = vbuf + bhbase + (size_t)kvw * WINSZ * HD;
#pragma unroll
        for (int j = 0; j < 4; ++j) {
            const int cc = tid + j * 256;
            const int s = cc >> 3, d0 = (cc & 7) * 8;   // cc&7 == lane&7 == l7
            const int sw = ((s >> 3) ^ l7) << 3 | (s & 7);
            half8 vvv = *(const half8*)(vsrc + cc * 8);
#pragma unroll
            for (int e = 0; e < 8; ++e)
                vt[(d0 + e) * 136 + sw] = vvv[e];
        }
        __syncthreads();

        const _Float16* ksrc = kbuf + bhbase + (size_t)kvw * WINSZ * HD;
        floatx4 sacc[2][8];
#pragma unroll
        for (int nt = 0; nt < 8; ++nt) {
            half8 b0 = *(const half8*)(ksrc + (nt * 16 + ln) * HD + qd * 8);
            half8 b1 = *(const half8*)(ksrc + (nt * 16 + ln) * HD + 32 + qd * 8);
#pragma unroll
            for (int mt = 0; mt < 2; ++mt) {
                floatx4 t = mfma16(qf[mt][0], b0, (floatx4){0.f, 0.f, 0.f, 0.f});
                sacc[mt][nt] = mfma16(qf[mt][1], b1, t);
            }
        }

        _Float16* pw = pl + wv * 32 * 136;
#pragma unroll
        for (int mt = 0; mt < 2; ++mt) {
#pragma unroll
            for (int r = 0; r < 4; ++r) {
                float mx = -3.0e38f;
#pragma unroll
                for (int nt = 0; nt < 8; ++nt)
                    mx = fmaxf(mx, sacc[mt][nt][r] * 0.125f);
                mx = qmax16(mx);
                const float mnew  = fmaxf(mrun[mt][r], mx);
                const float alpha = __expf(mrun[mt][r] - mnew);
                float rs = 0.f;
#pragma unroll
                for (int nt = 0; nt < 8; ++nt) {
                    const float pv = __expf(sacc[mt][nt][r] * 0.125f - mnew);
                    rs += pv;
                    pw[(mt * 16 + qd * 4 + r) * 136 + nt * 16 + ln] = (_Float16)pv;
                }
                rs = qsum16(rs);
                lrun[mt][r] = lrun[mt][r] * alpha + rs;
                mrun[mt][r] = mnew;
#pragma unroll
                for (int dt = 0; dt < 4; ++dt) oacc[mt][dt][r] *= alpha;
            }
        }

#pragma unroll
        for (int kt = 0; kt < 4; ++kt) {
            half8 pf0 = *(const half8*)(pw + ln * 136 + kt * 32 + qd * 8);
            half8 pf1 = *(const half8*)(pw + (16 + ln) * 136 + kt * 32 + qd * 8);
            __builtin_amdgcn_s_setprio(1);
#pragma unroll
            for (int dt = 0; dt < 4; ++dt) {
                const int d = dt * 16 + ln;
                const int slot = (kt * 4 + qd) ^ ((dt * 2 + h3) & 7);
                half8 vf = *(const half8*)&vt[d * 136 + (slot << 3)];
                oacc[0][dt] = mfma16(pf0, vf, oacc[0][dt]);
                oacc[1][dt] = mfma16(pf1, vf, oacc[1][dt]);
            }
            __builtin_amdgcn_s_setprio(0);
        }
    }

    const int b = bh >> 3, h = bh & 7;
#pragma unroll
    for (int mt = 0; mt < 2; ++mt) {
#pragma unroll
        for (int dt = 0; dt < 4; ++dt) {
#pragma unroll
            for (int r = 0; r < 4; ++r) {
                const int trow = w * WINSZ + wv * 32 + mt * 16 + qd * 4 + r;
                const int col  = h * HD + dt * 16 + ln;
                attn[((size_t)b * NN + trow) * DIM + col] =
                    (_Float16)(oacc[mt][dt][r] / lrun[mt][r]);
            }
        }
    }
}

// ---------------------------------------------------------------------------
extern "C" void kernel_launch(void* const* d_in, const int* in_sizes, int n_in,
                              void* d_out, int out_size, void* d_ws, size_t ws_size,
                              hipStream_t stream) {
    const float* x      = (const float*)d_in[0];
    const float* t_emb  = (const float*)d_in[1];
    const float* ln1_g  = (const float*)d_in[2];
    const float* ln1_b  = (const float*)d_in[3];
    const float* qkv_w  = (const float*)d_in[4];
    const float* qkv_b  = (const float*)d_in[5];
    const float* proj_w = (const float*)d_in[6];
    const float* proj_b = (const float*)d_in[7];
    const float* ln2_g  = (const float*)d_in[8];
    const float* ln2_b  = (const float*)d_in[9];
    const float* mlp_w1 = (const float*)d_in[10];
    const float* mlp_b1 = (const float*)d_in[11];
    const float* mlp_w2 = (const float*)d_in[12];
    const float* mlp_b2 = (const float*)d_in[13];
    const float* time_w = (const float*)d_in[14];
    const float* time_b = (const float*)d_in[15];
    float* out = (float*)d_out;

    char* p = (char*)d_ws;
    auto alloc = [&](size_t bytes) {
        char* r = p;
        p += (bytes + 255) & ~(size_t)255;
        return r;
    };
    float*    ss   = (float*)alloc(8 * 1024 * 4);
    _Float16* wq   = (_Float16*)alloc((size_t)1536 * 512 * 2);
    _Float16* wp   = (_Float16*)alloc((size_t)512 * 512 * 2);
    _Float16* w1t  = (_Float16*)alloc((size_t)2048 * 512 * 2);
    _Float16* w2t  = (_Float16*)alloc((size_t)512 * 2048 * 2);
    _Float16* h2   = (_Float16*)alloc((size_t)MROWS * 512 * 2);
    _Float16* x1h  = (_Float16*)alloc((size_t)MROWS * 512 * 2);
    _Float16* regA = (_Float16*)alloc((size_t)MROWS * 512 * 2);      // xn / attn
    _Float16* regB = (_Float16*)alloc((size_t)3 * MROWS * 512 * 2);  // q,k,v
    _Float16* xn     = regA;
    _Float16* attn   = regA;
    _Float16* qkvb   = regB;
    _Float16* hidden = regA;  // 268 MB = regA(67) + regB(201), both dead by then
    (void)ws_size; (void)in_sizes; (void)n_in; (void)out_size;

    // 1. weight casts/transposes (f32 [K][N] -> f16 [N][K]), LDS-tiled
    wcast_kernel<<<dim3(512 / 32, 1536 / 32), 256, 0, stream>>>(qkv_w, wq, 512, 1536);
    wcast_kernel<<<dim3(512 / 32, 512 / 32), 256, 0, stream>>>(proj_w, wp, 512, 512);
    wcast_kernel<<<dim3(512 / 32, 2048 / 32), 256, 0, stream>>>(mlp_w1, w1t, 512, 2048);
    wcast_kernel<<<dim3(2048 / 32, 512 / 32), 256, 0, stream>>>(mlp_w2, w2t, 2048, 512);
    // 2. time modulation
    time_ss_kernel<<<dim3(8, 8), 128, 0, stream>>>(t_emb, time_w, time_b, ss);
    // 3. LN1 + FiLM -> xn (f16)
    ln_kernel<<<dim3(MROWS / 4), 256, 0, stream>>>(x, ln1_g, ln1_b, ss, xn);
    // 4. QKV GEMM with q/k/v scatter  (256x128 tiles, 512 threads)
    gemm_bt<0><<<dim3(1536 / 128, MROWS / 256), 512, 0, stream>>>(
        xn, wq, qkv_b, 512, 1536, nullptr, nullptr, nullptr, qkvb);
    // 5. windowed attention -> attn (f16, [B][N][DIM])
    attn_kernel<<<dim3(NW, BB * HEADS), 256, 0, stream>>>(qkvb, attn);
    // 6. proj GEMM + residual(x f32) -> x1h (f16)
    gemm_bt<1><<<dim3(512 / 128, MROWS / 256), 512, 0, stream>>>(
        attn, wp, proj_b, 512, 512, x, nullptr, nullptr, x1h);
    // 7. LN2 (f16 in) -> h2 (f16)
    ln_h_kernel<<<dim3(MROWS / 4), 256, 0, stream>>>(x1h, ln2_g, ln2_b, h2);
    // 8. MLP1 + fast GELU -> hidden (f16)
    gemm_bt<2><<<dim3(2048 / 128, MROWS / 256), 512, 0, stream>>>(
        h2, w1t, mlp_b1, 512, 2048, nullptr, nullptr, nullptr, hidden);
    // 9. MLP2 + residual(x1h f16) -> out (f32)
    gemm_bt<3><<<dim3(512 / 128, MROWS / 256), 512, 0, stream>>>(
        hidden, w2t, mlp_b2, 2048, 512, nullptr, x1h, out, nullptr);
}